// Round 1
// baseline (13036.555 us; speedup 1.0000x reference)
//
#include <hip/hip_runtime.h>
#include <cstdint>

constexpr int BB = 128;   // batch
constexpr int SS = 512;   // source length
constexpr int DD = 512;   // hidden dim
constexpr int TT = 64;    // decode steps
constexpr int OO = 3;     // output dim

__device__ __forceinline__ float tanh_fast(float x) {
  float e = __expf(2.0f * x);
  return 1.0f - 2.0f / (e + 1.0f);
}
__device__ __forceinline__ float sigmoid_fast(float x) {
  return 1.0f / (1.0f + __expf(-x));
}

// ---------------------------------------------------------------------------
// Generic tiled fp32 GEMM body: C[m,n] = sum_k A[m,k] * Bw[n,k] + bias[n]
// (B operand stored row-major as [N,K], i.e. C = A @ Bw^T + bias)
// ---------------------------------------------------------------------------
template<int BM, int BN, int BK, int TM, int TN>
__device__ __forceinline__ void gemm_body(
    const float* __restrict__ A, int lda,
    const float* __restrict__ Bw, int ldb,
    const float* __restrict__ bias,
    float* __restrict__ C, int ldc, int K) {
  constexpr int TX = BN / TN, TY = BM / TM;
  static_assert(TX * TY == 256, "tile/thread mismatch");
  __shared__ float As[BK][BM + 4];
  __shared__ float Bs[BK][BN + 4];
  const int tid = threadIdx.x;
  const int bm = blockIdx.y * BM, bn = blockIdx.x * BN;
  const int tx = tid % TX, ty = tid / TX;
  float acc[TM][TN];
#pragma unroll
  for (int i = 0; i < TM; ++i)
#pragma unroll
    for (int j = 0; j < TN; ++j) acc[i][j] = 0.f;

  for (int k0 = 0; k0 < K; k0 += BK) {
#pragma unroll
    for (int i = 0; i < BM * BK / 256; ++i) {
      int idx = tid + i * 256;
      int m = idx / BK, k = idx % BK;
      As[k][m] = A[(size_t)(bm + m) * lda + k0 + k];
    }
#pragma unroll
    for (int i = 0; i < BN * BK / 256; ++i) {
      int idx = tid + i * 256;
      int n = idx / BK, k = idx % BK;
      Bs[k][n] = Bw[(size_t)(bn + n) * ldb + k0 + k];
    }
    __syncthreads();
#pragma unroll
    for (int k = 0; k < BK; ++k) {
      float ra[TM], rb[TN];
#pragma unroll
      for (int i = 0; i < TM; ++i) ra[i] = As[k][ty * TM + i];
#pragma unroll
      for (int j = 0; j < TN; ++j) rb[j] = Bs[k][tx * TN + j];
#pragma unroll
      for (int i = 0; i < TM; ++i)
#pragma unroll
        for (int j = 0; j < TN; ++j) acc[i][j] += ra[i] * rb[j];
    }
    __syncthreads();
  }
#pragma unroll
  for (int i = 0; i < TM; ++i) {
    int m = bm + ty * TM + i;
#pragma unroll
    for (int j = 0; j < TN; ++j) {
      int n = bn + tx * TN + j;
      C[(size_t)m * ldc + n] = acc[i][j] + bias[n];
    }
  }
}

// Uk = e_all(view [B*S, D]) @ Ua^T + bu   -> [B*S, D]
__global__ __launch_bounds__(256) void gemm_uk(const float* __restrict__ e_all,
                                               const float* __restrict__ Ua,
                                               const float* __restrict__ bu,
                                               float* __restrict__ Uk) {
  gemm_body<128, 128, 16, 8, 8>(e_all, DD, Ua, DD, bu, Uk, DD, DD);
}

// gi = ctx @ Wih_main^T + b_ih ; gh = h @ W_hh^T + b_hh   (blockIdx.z selects)
__global__ __launch_bounds__(256) void gemm_gates(
    const float* __restrict__ ctx, const float* __restrict__ h,
    const float* __restrict__ Wm, const float* __restrict__ Whh,
    const float* __restrict__ bih, const float* __restrict__ bhh,
    float* __restrict__ gi, float* __restrict__ gh) {
  if (blockIdx.z == 0)
    gemm_body<32, 64, 32, 2, 4>(ctx, DD, Wm, DD, bih, gi, 3 * DD, DD);
  else
    gemm_body<32, 64, 32, 2, 4>(h, DD, Whh, DD, bhh, gh, 3 * DD, DD);
}

// Repack W_ih [3D, D+3] -> Wm [3D, D] (contiguous, aligned) + Wx [3D, 3]
__global__ void prep_wih(const float* __restrict__ W_ih,
                         float* __restrict__ Wm, float* __restrict__ Wx) {
  int idx = blockIdx.x * 256 + threadIdx.x;
  const int total = 3 * DD * (DD + OO);
  if (idx >= total) return;
  int j = idx / (DD + OO), k = idx % (DD + OO);
  float v = W_ih[idx];
  if (k < DD) Wm[(size_t)j * DD + k] = v;
  else        Wx[j * OO + (k - DD)] = v;
}

// ---------------------------------------------------------------------------
// Fused per-step attention: q = h@Wa^T+ba ; scores = va . tanh(q+Uk) + vb ;
// softmax ; ctx = w . e_all ; writes w into cross_attn output slice.
// One block per batch row, 1024 threads.
// ---------------------------------------------------------------------------
__global__ __launch_bounds__(1024) void attn_step(
    const float* __restrict__ Uk, const float* __restrict__ e_all,
    const float* __restrict__ h,  const float* __restrict__ Wa,
    const float* __restrict__ ba, const float* __restrict__ va,
    const float* __restrict__ vb_p,
    float* __restrict__ ctx, float* __restrict__ attn_out, int t) {
  const int b = blockIdx.x;
  __shared__ __align__(16) float sh_h[DD];
  __shared__ __align__(16) float sh_q[DD];
  __shared__ __align__(16) float sh_va[DD];
  __shared__ __align__(16) float sh_s[SS];
  __shared__ __align__(16) float sh_c[DD];
  __shared__ float red[16];
  const int tid = threadIdx.x;

  for (int i = tid; i < DD; i += 1024) {
    sh_h[i] = h[b * DD + i];
    sh_va[i] = va[i];
  }
  __syncthreads();

  const int g = tid >> 4, l16 = tid & 15;

  // ---- q[e] = sum_d Wa[e,d]*h[d] + ba[e] : 16 lanes per output row
  {
    const float4* hh = (const float4*)sh_h;
    for (int e = g; e < DD; e += 64) {
      const float4* wrow = (const float4*)(Wa + (size_t)e * DD);
      float acc = 0.f;
      for (int i = l16; i < DD / 4; i += 16) {
        float4 w4 = wrow[i], h4 = hh[i];
        acc += w4.x * h4.x + w4.y * h4.y + w4.z * h4.z + w4.w * h4.w;
      }
#pragma unroll
      for (int off = 8; off; off >>= 1) acc += __shfl_down(acc, off, 16);
      if (l16 == 0) sh_q[e] = acc + ba[e];
    }
  }
  __syncthreads();

  // ---- scores[s] = sum_d va[d]*tanh(q[d]+Uk[b,s,d]) + vb
  {
    const float vb = vb_p[0];
    const float4* q4 = (const float4*)sh_q;
    const float4* v4 = (const float4*)sh_va;
    for (int s = g; s < SS; s += 64) {
      const float4* row = (const float4*)(Uk + ((size_t)b * SS + s) * DD);
      float acc = 0.f;
      for (int i = l16; i < DD / 4; i += 16) {
        float4 u = row[i], qq = q4[i], vv = v4[i];
        acc += vv.x * tanh_fast(qq.x + u.x);
        acc += vv.y * tanh_fast(qq.y + u.y);
        acc += vv.z * tanh_fast(qq.z + u.z);
        acc += vv.w * tanh_fast(qq.w + u.w);
      }
#pragma unroll
      for (int off = 8; off; off >>= 1) acc += __shfl_down(acc, off, 16);
      if (l16 == 0) sh_s[s] = acc + vb;
    }
  }
  __syncthreads();

  // ---- softmax over SS=512 values (threads >= SS contribute identity)
  float v = (tid < SS) ? sh_s[tid] : -3.4e38f;
  float m = v;
#pragma unroll
  for (int off = 32; off; off >>= 1) m = fmaxf(m, __shfl_xor(m, off));
  if ((tid & 63) == 0) red[tid >> 6] = m;
  __syncthreads();
  if (tid < 16) {
    float mm = red[tid];
#pragma unroll
    for (int off = 8; off; off >>= 1) mm = fmaxf(mm, __shfl_xor(mm, off));
    red[tid] = mm;
  }
  __syncthreads();
  m = red[0];
  float e_ = (tid < SS) ? __expf(v - m) : 0.f;
  float ssum = e_;
#pragma unroll
  for (int off = 32; off; off >>= 1) ssum += __shfl_xor(ssum, off);
  __syncthreads();  // everyone done reading red[0]
  if ((tid & 63) == 0) red[tid >> 6] = ssum;
  __syncthreads();
  if (tid < 16) {
    float s2 = red[tid];
#pragma unroll
    for (int off = 8; off; off >>= 1) s2 += __shfl_xor(s2, off);
    red[tid] = s2;
  }
  __syncthreads();
  const float inv = 1.0f / red[0];
  if (tid < SS) {
    float w = e_ * inv;
    sh_s[tid] = w;
    attn_out[((size_t)b * TT + t) * SS + tid] = w;
  }
  __syncthreads();

  // ---- ctx[d] = sum_s w[s] * e_all[b,s,d] ; split s over two halves
  {
    const int d = tid & (DD - 1);
    const int half = tid >> 9;
    const float* eB = e_all + (size_t)b * SS * DD;
    float acc = 0.f;
    const int s0 = half * (SS / 2), s1 = s0 + SS / 2;
    for (int s = s0; s < s1; ++s) acc += sh_s[s] * eB[(size_t)s * DD + d];
    if (half == 0) {
      sh_c[d] = acc;
    }
    __syncthreads();
    if (half == 1) ctx[b * DD + d] = sh_c[d] + acc;
  }
}

// ---------------------------------------------------------------------------
// Fused GRU pointwise + output projection. One block per batch row, 512 thr.
// ---------------------------------------------------------------------------
__global__ __launch_bounds__(512) void gru_update(
    const float* __restrict__ gi, const float* __restrict__ gh,
    float* __restrict__ h,
    const float* __restrict__ Wx, const float* __restrict__ target,
    const float* __restrict__ W_out, const float* __restrict__ b_out,
    float* __restrict__ out_d, float* __restrict__ out_hT, int t) {
  const int b = blockIdx.x;
  const int d = threadIdx.x;
  __shared__ __align__(16) float sh_hn[DD];

  float x0 = 0.f, x1 = 0.f, x2 = 0.f;
  if (t > 0) {
    const float* xp = target + ((size_t)b * TT + (t - 1)) * OO;
    x0 = xp[0]; x1 = xp[1]; x2 = xp[2];
  }
  const float* gib = gi + (size_t)b * 3 * DD;
  const float* ghb = gh + (size_t)b * 3 * DD;

  const float* wr = Wx + (size_t)d * OO;
  const float* wz = Wx + (size_t)(DD + d) * OO;
  const float* wn = Wx + (size_t)(2 * DD + d) * OO;
  float ir = gib[d]          + x0 * wr[0] + x1 * wr[1] + x2 * wr[2];
  float iz = gib[DD + d]     + x0 * wz[0] + x1 * wz[1] + x2 * wz[2];
  float in_ = gib[2 * DD + d] + x0 * wn[0] + x1 * wn[1] + x2 * wn[2];
  float hr = ghb[d], hz = ghb[DD + d], hn = ghb[2 * DD + d];

  float r = sigmoid_fast(ir + hr);
  float z = sigmoid_fast(iz + hz);
  float n = tanh_fast(in_ + r * hn);
  float hp = h[(size_t)b * DD + d];
  float hnew = (1.f - z) * n + z * hp;
  h[(size_t)b * DD + d] = hnew;
  sh_hn[d] = hnew;
  if (t == TT - 1) out_hT[(size_t)b * DD + d] = hnew;
  __syncthreads();

  // out[b,t,o] = sh_hn . W_out[o,:] + b_out[o] ; waves 0..2 handle o=0..2
  const int wave = d >> 6, lane = d & 63;
  if (wave < OO) {
    const float* wrow = W_out + (size_t)wave * DD;
    float acc = 0.f;
    for (int i = lane; i < DD; i += 64) acc += sh_hn[i] * wrow[i];
#pragma unroll
    for (int off = 32; off; off >>= 1) acc += __shfl_xor(acc, off);
    if (lane == 0) out_d[((size_t)b * TT + t) * OO + wave] = acc + b_out[wave];
  }
}

// ---------------------------------------------------------------------------
extern "C" void kernel_launch(void* const* d_in, const int* in_sizes, int n_in,
                              void* d_out, int out_size, void* d_ws, size_t ws_size,
                              hipStream_t stream) {
  const float* e_all  = (const float*)d_in[0];
  const float* e_last = (const float*)d_in[1];
  const float* target = (const float*)d_in[2];
  const float* Wa     = (const float*)d_in[3];
  const float* ba     = (const float*)d_in[4];
  const float* Ua     = (const float*)d_in[5];
  const float* bu     = (const float*)d_in[6];
  const float* Va_w   = (const float*)d_in[7];
  const float* Va_b   = (const float*)d_in[8];
  const float* W_ih   = (const float*)d_in[9];
  const float* b_ih   = (const float*)d_in[10];
  const float* W_hh   = (const float*)d_in[11];
  const float* b_hh   = (const float*)d_in[12];
  const float* W_out  = (const float*)d_in[13];
  const float* b_out  = (const float*)d_in[14];

  float* out      = (float*)d_out;
  float* out_d    = out;                         // [B,T,3]
  float* out_hT   = out + (size_t)BB * TT * OO;  // [1,B,D]
  float* out_attn = out_hT + (size_t)BB * DD;    // [B,T,S]

  float* ws  = (float*)d_ws;
  float* Uk  = ws;                                   // B*S*D
  float* h   = Uk + (size_t)BB * SS * DD;            // B*D
  float* ctx = h + (size_t)BB * DD;                  // B*D
  float* gi  = ctx + (size_t)BB * DD;                // B*3D
  float* gh  = gi + (size_t)BB * 3 * DD;             // B*3D
  float* Wm  = gh + (size_t)BB * 3 * DD;             // 3D*D
  float* Wx  = Wm + (size_t)3 * DD * DD;             // 3D*3

  // one-time per launch (ws is re-poisoned before every call)
  {
    const int total = 3 * DD * (DD + OO);
    prep_wih<<<(total + 255) / 256, 256, 0, stream>>>(W_ih, Wm, Wx);
  }
  gemm_uk<<<dim3(DD / 128, (BB * SS) / 128), 256, 0, stream>>>(e_all, Ua, bu, Uk);
  hipMemcpyAsync(h, e_last, (size_t)BB * DD * sizeof(float),
                 hipMemcpyDeviceToDevice, stream);

  for (int t = 0; t < TT; ++t) {
    attn_step<<<BB, 1024, 0, stream>>>(Uk, e_all, h, Wa, ba, Va_w, Va_b,
                                       ctx, out_attn, t);
    gemm_gates<<<dim3((3 * DD) / 64, BB / 32, 2), 256, 0, stream>>>(
        ctx, h, Wm, W_hh, b_ih, b_hh, gi, gh);
    gru_update<<<BB, 512, 0, stream>>>(gi, gh, h, Wx, target, W_out, b_out,
                                       out_d, out_hT, t);
  }
}

// Round 3
// 6341.054 us; speedup vs baseline: 2.0559x; 2.0559x over previous
//
#include <hip/hip_runtime.h>
#include <cstdint>

constexpr int BB = 128;   // batch
constexpr int SS = 512;   // source length
constexpr int DD = 512;   // hidden dim
constexpr int TT = 64;    // decode steps
constexpr int OO = 3;     // output dim

__device__ __forceinline__ float tanh_fast(float x) {
  float e = __expf(2.0f * x);
  return 1.0f - 2.0f / (e + 1.0f);
}
__device__ __forceinline__ float sigmoid_fast(float x) {
  return 1.0f / (1.0f + __expf(-x));
}
__device__ __forceinline__ unsigned short f2bf(float f) {
  uint32_t u = __float_as_uint(f);
  uint32_t r = (u + 0x7FFFu + ((u >> 16) & 1u)) >> 16;  // RNE
  return (unsigned short)r;
}
// unpack one uint32 holding two bf16 (little-endian: .x = low half)
__device__ __forceinline__ float2 bfx2(uint32_t u) {
  float2 r;
  r.x = __uint_as_float(u << 16);
  r.y = __uint_as_float(u & 0xFFFF0000u);
  return r;
}

// ---------------------------------------------------------------------------
// Generic tiled fp32 GEMM body: C[m,n] = sum_k A[m,k] * Bw[n,k] + bias[n]
// ---------------------------------------------------------------------------
template<int BM, int BN, int BK, int TM, int TN>
__device__ __forceinline__ void gemm_body(
    const float* __restrict__ A, int lda,
    const float* __restrict__ Bw, int ldb,
    const float* __restrict__ bias,
    float* __restrict__ C, int ldc, int K) {
  constexpr int TX = BN / TN, TY = BM / TM;
  static_assert(TX * TY == 256, "tile/thread mismatch");
  __shared__ float As[BK][BM + 4];
  __shared__ float Bs[BK][BN + 4];
  const int tid = threadIdx.x;
  const int bm = blockIdx.y * BM, bn = blockIdx.x * BN;
  const int tx = tid % TX, ty = tid / TX;
  float acc[TM][TN];
#pragma unroll
  for (int i = 0; i < TM; ++i)
#pragma unroll
    for (int j = 0; j < TN; ++j) acc[i][j] = 0.f;

  for (int k0 = 0; k0 < K; k0 += BK) {
#pragma unroll
    for (int i = 0; i < BM * BK / 256; ++i) {
      int idx = tid + i * 256;
      int m = idx / BK, k = idx % BK;
      As[k][m] = A[(size_t)(bm + m) * lda + k0 + k];
    }
#pragma unroll
    for (int i = 0; i < BN * BK / 256; ++i) {
      int idx = tid + i * 256;
      int n = idx / BK, k = idx % BK;
      Bs[k][n] = Bw[(size_t)(bn + n) * ldb + k0 + k];
    }
    __syncthreads();
#pragma unroll
    for (int k = 0; k < BK; ++k) {
      float ra[TM], rb[TN];
#pragma unroll
      for (int i = 0; i < TM; ++i) ra[i] = As[k][ty * TM + i];
#pragma unroll
      for (int j = 0; j < TN; ++j) rb[j] = Bs[k][tx * TN + j];
#pragma unroll
      for (int i = 0; i < TM; ++i)
#pragma unroll
        for (int j = 0; j < TN; ++j) acc[i][j] += ra[i] * rb[j];
    }
    __syncthreads();
  }
#pragma unroll
  for (int i = 0; i < TM; ++i) {
    int m = bm + ty * TM + i;
#pragma unroll
    for (int j = 0; j < TN; ++j) {
      int n = bn + tx * TN + j;
      C[(size_t)m * ldc + n] = acc[i][j] + bias[n];
    }
  }
}

// Uk = e_all(view [B*S, D]) @ Ua^T + bu -> bf16 [B*S, D]
__global__ __launch_bounds__(256) void gemm_uk(
    const float* __restrict__ A, const float* __restrict__ Bw,
    const float* __restrict__ bias, unsigned short* __restrict__ Uk) {
  constexpr int BM = 128, BN = 128, BK = 16, TM = 8, TN = 8, TX = 16;
  __shared__ float As[BK][BM + 4];
  __shared__ float Bs[BK][BN + 4];
  const int tid = threadIdx.x;
  const int bm = blockIdx.y * BM, bn = blockIdx.x * BN;
  const int tx = tid % TX, ty = tid / TX;
  float acc[TM][TN];
#pragma unroll
  for (int i = 0; i < TM; ++i)
#pragma unroll
    for (int j = 0; j < TN; ++j) acc[i][j] = 0.f;

  for (int k0 = 0; k0 < DD; k0 += BK) {
#pragma unroll
    for (int i = 0; i < BM * BK / 256; ++i) {
      int idx = tid + i * 256;
      int m = idx / BK, k = idx % BK;
      As[k][m] = A[(size_t)(bm + m) * DD + k0 + k];
    }
#pragma unroll
    for (int i = 0; i < BN * BK / 256; ++i) {
      int idx = tid + i * 256;
      int n = idx / BK, k = idx % BK;
      Bs[k][n] = Bw[(size_t)(bn + n) * DD + k0 + k];
    }
    __syncthreads();
#pragma unroll
    for (int k = 0; k < BK; ++k) {
      float ra[TM], rb[TN];
#pragma unroll
      for (int i = 0; i < TM; ++i) ra[i] = As[k][ty * TM + i];
#pragma unroll
      for (int j = 0; j < TN; ++j) rb[j] = Bs[k][tx * TN + j];
#pragma unroll
      for (int i = 0; i < TM; ++i)
#pragma unroll
        for (int j = 0; j < TN; ++j) acc[i][j] += ra[i] * rb[j];
    }
    __syncthreads();
  }
#pragma unroll
  for (int i = 0; i < TM; ++i) {
    int m = bm + ty * TM + i;
    uint32_t* row = (uint32_t*)(Uk + (size_t)m * DD + bn + tx * TN);
#pragma unroll
    for (int j = 0; j < TN / 2; ++j) {
      int n = bn + tx * TN + 2 * j;
      uint32_t lo = f2bf(acc[i][2 * j] + bias[n]);
      uint32_t hi = f2bf(acc[i][2 * j + 1] + bias[n + 1]);
      row[j] = lo | (hi << 16);
    }
  }
}

// gi = ctx @ Wm^T + b_ih ; gh = h @ W_hh^T + b_hh  (blockIdx.z selects)
__global__ __launch_bounds__(256) void gemm_gates(
    const float* __restrict__ ctx, const float* __restrict__ h,
    const float* __restrict__ Wm, const float* __restrict__ Whh,
    const float* __restrict__ bih, const float* __restrict__ bhh,
    float* __restrict__ gi, float* __restrict__ gh) {
  if (blockIdx.z == 0)
    gemm_body<32, 64, 32, 2, 4>(ctx, DD, Wm, DD, bih, gi, 3 * DD, DD);
  else
    gemm_body<32, 64, 32, 2, 4>(h, DD, Whh, DD, bhh, gh, 3 * DD, DD);
}

// Repack W_ih [3D, D+3] -> Wm [3D, D] + Wx [3D, 3]
__global__ void prep_wih(const float* __restrict__ W_ih,
                         float* __restrict__ Wm, float* __restrict__ Wx) {
  int idx = blockIdx.x * 256 + threadIdx.x;
  const int total = 3 * DD * (DD + OO);
  if (idx >= total) return;
  int j = idx / (DD + OO), k = idx % (DD + OO);
  float v = W_ih[idx];
  if (k < DD) Wm[(size_t)j * DD + k] = v;
  else        Wx[j * OO + (k - DD)] = v;
}

// WaT[d, e] = Wa[e, d]
__global__ void transp_wa(const float* __restrict__ Wa, float* __restrict__ WaT) {
  int idx = blockIdx.x * 256 + threadIdx.x;  // e*512+d
  int e = idx >> 9, d = idx & (DD - 1);
  WaT[(size_t)d * DD + e] = Wa[idx];
}

// q[b,:] = h[b,:] @ Wa^T + ba   (initial step; WaT coalesced)
__global__ __launch_bounds__(512) void qproj(const float* __restrict__ h,
                                             const float* __restrict__ WaT,
                                             const float* __restrict__ ba,
                                             float* __restrict__ q) {
  const int b = blockIdx.x, e = threadIdx.x;
  __shared__ float sh[DD];
  sh[e] = h[(size_t)b * DD + e];
  __syncthreads();
  float acc = 0.f;
#pragma unroll 8
  for (int d = 0; d < DD; ++d) acc += WaT[(size_t)d * DD + e] * sh[d];
  q[(size_t)b * DD + e] = acc + ba[e];
}

// ---------------------------------------------------------------------------
// scores[b,s] = va . tanh(q[b]+Uk[b,s]) + vb ; grid (S/64, B), 256 thr
// ---------------------------------------------------------------------------
__global__ __launch_bounds__(256) void attn_scores(
    const unsigned short* __restrict__ Uk_bf, const float* __restrict__ q,
    const float* __restrict__ va, const float* __restrict__ vb_p,
    float* __restrict__ scores) {
  const int b = blockIdx.y;
  const int s0 = blockIdx.x * 64;
  __shared__ float4 sh_q[DD / 4];
  __shared__ float4 sh_va[DD / 4];
  const int tid = threadIdx.x;
  if (tid < DD / 4) {
    sh_q[tid] = ((const float4*)(q + (size_t)b * DD))[tid];
    sh_va[tid] = ((const float4*)va)[tid];
  }
  __syncthreads();
  const float vb = vb_p[0];
  const int g = tid >> 4, l = tid & 15;
#pragma unroll
  for (int i = 0; i < 4; ++i) {
    const int s = s0 + 16 * i + g;
    const uint2* row = (const uint2*)(Uk_bf + ((size_t)b * SS + s) * DD);
    float acc = 0.f;
#pragma unroll
    for (int j = 0; j < 8; ++j) {
      uint2 u = row[l + 16 * j];
      float4 qq = sh_q[l + 16 * j];
      float4 vv = sh_va[l + 16 * j];
      float2 e0 = bfx2(u.x), e1 = bfx2(u.y);
      acc += vv.x * tanh_fast(qq.x + e0.x);
      acc += vv.y * tanh_fast(qq.y + e0.y);
      acc += vv.z * tanh_fast(qq.z + e1.x);
      acc += vv.w * tanh_fast(qq.w + e1.y);
    }
#pragma unroll
    for (int off = 8; off; off >>= 1) acc += __shfl_down(acc, off, 16);
    if (l == 0) scores[(size_t)b * SS + s] = acc + vb;
  }
}

// ---------------------------------------------------------------------------
// softmax(scores[b]) -> w ; ctx[b, d-chunk] = w . e_all ; grid (4, B), 256 thr
// ---------------------------------------------------------------------------
__global__ __launch_bounds__(256) void attn_ctx(
    const float* __restrict__ e_all, const float* __restrict__ scores,
    float* __restrict__ ctx, float* __restrict__ attn_out, int t) {
  const int b = blockIdx.y, dc = blockIdx.x;
  __shared__ float w[SS];
  __shared__ float red[8];
  __shared__ float2 part[4][64];
  const int tid = threadIdx.x;

  float v0 = scores[(size_t)b * SS + tid];
  float v1 = scores[(size_t)b * SS + 256 + tid];
  float m = fmaxf(v0, v1);
#pragma unroll
  for (int off = 32; off; off >>= 1) m = fmaxf(m, __shfl_xor(m, off));
  if ((tid & 63) == 0) red[tid >> 6] = m;
  __syncthreads();
  m = fmaxf(fmaxf(red[0], red[1]), fmaxf(red[2], red[3]));
  float e0 = __expf(v0 - m), e1 = __expf(v1 - m);
  float ss = e0 + e1;
#pragma unroll
  for (int off = 32; off; off >>= 1) ss += __shfl_xor(ss, off);
  __syncthreads();
  if ((tid & 63) == 0) red[tid >> 6] = ss;
  __syncthreads();
  const float inv = 1.f / (red[0] + red[1] + red[2] + red[3]);
  float w0 = e0 * inv, w1 = e1 * inv;
  w[tid] = w0;
  w[tid + 256] = w1;
  if (dc == 0) {
    float* ao = attn_out + ((size_t)b * TT + t) * SS;
    ao[tid] = w0;
    ao[tid + 256] = w1;
  }
  __syncthreads();

  // ctx over d-chunk of 128 columns; 4 s-quarters x 64 lanes (2 cols each)
  const int qrt = tid >> 6, lane = tid & 63;
  const int d0 = dc * 128;
  const size_t base = (size_t)b * SS * DD + d0 + 2 * lane;
  float2 acc = {0.f, 0.f};
  const int sBeg = qrt * 128, sEnd = sBeg + 128;
  for (int s = sBeg; s < sEnd; ++s) {
    float2 e = *(const float2*)(e_all + base + (size_t)s * DD);
    float ws = w[s];
    acc.x += ws * e.x;
    acc.y += ws * e.y;
  }
  part[qrt][lane] = acc;
  __syncthreads();
  if (tid < 64) {
    float2 a = part[0][tid], b2 = part[1][tid], c = part[2][tid], d = part[3][tid];
    float2 r;
    r.x = a.x + b2.x + c.x + d.x;
    r.y = a.y + b2.y + c.y + d.y;
    ((float2*)(ctx + (size_t)b * DD + d0))[tid] = r;
  }
}

// ---------------------------------------------------------------------------
// GRU pointwise + output projection + q for next step. One block per b.
// ---------------------------------------------------------------------------
__global__ __launch_bounds__(512) void gru_update(
    const float* __restrict__ gi, const float* __restrict__ gh,
    float* __restrict__ h,
    const float* __restrict__ Wx, const float* __restrict__ target,
    const float* __restrict__ W_out, const float* __restrict__ b_out,
    const float* __restrict__ WaT, const float* __restrict__ ba,
    float* __restrict__ q,
    float* __restrict__ out_d, float* __restrict__ out_hT, int t) {
  const int b = blockIdx.x;
  const int d = threadIdx.x;
  __shared__ __align__(16) float sh_hn[DD];

  float x0 = 0.f, x1 = 0.f, x2 = 0.f;
  if (t > 0) {
    const float* xp = target + ((size_t)b * TT + (t - 1)) * OO;
    x0 = xp[0]; x1 = xp[1]; x2 = xp[2];
  }
  const float* gib = gi + (size_t)b * 3 * DD;
  const float* ghb = gh + (size_t)b * 3 * DD;

  const float* wr = Wx + (size_t)d * OO;
  const float* wz = Wx + (size_t)(DD + d) * OO;
  const float* wn = Wx + (size_t)(2 * DD + d) * OO;
  float ir  = gib[d]          + x0 * wr[0] + x1 * wr[1] + x2 * wr[2];
  float iz  = gib[DD + d]     + x0 * wz[0] + x1 * wz[1] + x2 * wz[2];
  float in_ = gib[2 * DD + d] + x0 * wn[0] + x1 * wn[1] + x2 * wn[2];
  float hr = ghb[d], hz = ghb[DD + d], hn = ghb[2 * DD + d];

  float r = sigmoid_fast(ir + hr);
  float z = sigmoid_fast(iz + hz);
  float n = tanh_fast(in_ + r * hn);
  float hp = h[(size_t)b * DD + d];
  float hnew = (1.f - z) * n + z * hp;
  h[(size_t)b * DD + d] = hnew;
  sh_hn[d] = hnew;
  if (t == TT - 1) out_hT[(size_t)b * DD + d] = hnew;
  __syncthreads();

  // out[b,t,o]
  const int wave = d >> 6, lane = d & 63;
  if (wave < OO) {
    const float* wrow = W_out + (size_t)wave * DD;
    float acc = 0.f;
    for (int i = lane; i < DD; i += 64) acc += sh_hn[i] * wrow[i];
#pragma unroll
    for (int off = 32; off; off >>= 1) acc += __shfl_xor(acc, off);
    if (lane == 0) out_d[((size_t)b * TT + t) * OO + wave] = acc + b_out[wave];
  }

  // q_next[b,e] = sh_hn . WaT[:,e] + ba[e]
  float accq = 0.f;
#pragma unroll 8
  for (int dd = 0; dd < DD; ++dd) accq += WaT[(size_t)dd * DD + d] * sh_hn[dd];
  q[(size_t)b * DD + d] = accq + ba[d];
}

// ---------------------------------------------------------------------------
extern "C" void kernel_launch(void* const* d_in, const int* in_sizes, int n_in,
                              void* d_out, int out_size, void* d_ws, size_t ws_size,
                              hipStream_t stream) {
  const float* e_all  = (const float*)d_in[0];
  const float* e_last = (const float*)d_in[1];
  const float* target = (const float*)d_in[2];
  const float* Wa     = (const float*)d_in[3];
  const float* ba     = (const float*)d_in[4];
  const float* Ua     = (const float*)d_in[5];
  const float* bu     = (const float*)d_in[6];
  const float* Va_w   = (const float*)d_in[7];
  const float* Va_b   = (const float*)d_in[8];
  const float* W_ih   = (const float*)d_in[9];
  const float* b_ih   = (const float*)d_in[10];
  const float* W_hh   = (const float*)d_in[11];
  const float* b_hh   = (const float*)d_in[12];
  const float* W_out  = (const float*)d_in[13];
  const float* b_out  = (const float*)d_in[14];

  float* out      = (float*)d_out;
  float* out_d    = out;                         // [B,T,3]
  float* out_hT   = out + (size_t)BB * TT * OO;  // [1,B,D]
  float* out_attn = out_hT + (size_t)BB * DD;    // [B,T,S]

  // Workspace layout (total ~74 MB; R1's 139.4 MB worked, R2's 141 MB broke
  // post-timing validation -> suspected d_ws overflow; stay far below).
  char* wsB = (char*)d_ws;
  unsigned short* Uk_bf = (unsigned short*)wsB;     // B*S*D bf16 = 67.1 MB
  float* fws = (float*)(wsB + (size_t)BB * SS * DD * 2);
  float* scores = fws;                            // B*S
  float* q   = scores + (size_t)BB * SS;          // B*D
  float* h   = q + (size_t)BB * DD;               // B*D
  float* ctx = h + (size_t)BB * DD;               // B*D
  float* gi  = ctx + (size_t)BB * DD;             // B*3D
  float* gh  = gi + (size_t)BB * 3 * DD;          // B*3D
  float* Wm  = gh + (size_t)BB * 3 * DD;          // 3D*D
  float* Wx  = Wm + (size_t)3 * DD * DD;          // 3D*3
  float* WaT = Wx + (size_t)3 * DD * OO;          // D*D

  {
    const int total = 3 * DD * (DD + OO);
    prep_wih<<<(total + 255) / 256, 256, 0, stream>>>(W_ih, Wm, Wx);
  }
  transp_wa<<<(DD * DD) / 256, 256, 0, stream>>>(Wa, WaT);
  gemm_uk<<<dim3(DD / 128, (BB * SS) / 128), 256, 0, stream>>>(e_all, Ua, bu, Uk_bf);
  hipMemcpyAsync(h, e_last, (size_t)BB * DD * sizeof(float),
                 hipMemcpyDeviceToDevice, stream);
  qproj<<<BB, 512, 0, stream>>>(h, WaT, ba, q);

  for (int t = 0; t < TT; ++t) {
    attn_scores<<<dim3(SS / 64, BB), 256, 0, stream>>>(Uk_bf, q, Va_w, Va_b, scores);
    attn_ctx<<<dim3(4, BB), 256, 0, stream>>>(e_all, scores, ctx, out_attn, t);
    gemm_gates<<<dim3((3 * DD) / 64, BB / 32, 2), 256, 0, stream>>>(
        ctx, h, Wm, W_hh, b_ih, b_hh, gi, gh);
    gru_update<<<BB, 512, 0, stream>>>(gi, gh, h, Wx, target, W_out, b_out,
                                       WaT, ba, q, out_d, out_hT, t);
  }
}